// Round 6
// baseline (434.131 us; speedup 1.0000x reference)
//
#include <hip/hip_runtime.h>
#include <hip/hip_bf16.h>

typedef __bf16 bf16;
typedef __attribute__((ext_vector_type(2))) __bf16 bf16x2;
typedef __attribute__((ext_vector_type(8))) __bf16 bf16x8;
typedef __attribute__((ext_vector_type(4))) float f32x4;
typedef __attribute__((ext_vector_type(16))) float f32x16;

#define MFMA16(a, b, c) __builtin_amdgcn_mfma_f32_16x16x32_bf16((a), (b), (c), 0, 0, 0)
#define MFMA32(a, b, c) __builtin_amdgcn_mfma_f32_32x32x16_bf16((a), (b), (c), 0, 0, 0)

// Problem constants: N=4, L=2048, E=512, H=8, D=64, FF=2048, tokens = 8192.

__device__ __forceinline__ void load_lds16(const bf16* g, bf16* l) {
    __builtin_amdgcn_global_load_lds(
        (const __attribute__((address_space(1))) void*)g,
        (__attribute__((address_space(3))) void*)l, 16, 0, 0);
}

__device__ __forceinline__ float fexp2(float x) { return __builtin_amdgcn_exp2f(x); }

// ---------------- all weight transposes in ONE kernel (768 blocks) ----------------
__global__ void cvt_all(const float* __restrict__ wq, const float* __restrict__ wk,
                        const float* __restrict__ wv, const float* __restrict__ wo,
                        const float* __restrict__ w1, const float* __restrict__ w2,
                        bf16* __restrict__ wqkv_t, bf16* __restrict__ wo_t,
                        bf16* __restrict__ w1_t, bf16* __restrict__ w2_t) {
    __shared__ float t[64][65];
    const int b = blockIdx.x;
    const float* src; bf16* dst;
    int sstride, dstride, r0, c0, dr0;
    if (b < 192) {            // qkv: dst [1536][512]
        int bx = b % 24, by = b / 24;
        int j0 = bx * 64;
        src = (j0 < 512) ? wq : (j0 < 1024) ? wk : wv;
        sstride = 512; r0 = by * 64; c0 = j0 & 511;
        dst = wqkv_t; dstride = 512; dr0 = j0;
    } else if (b < 256) {     // wo
        int tt = b - 192; int bx = tt % 8, by = tt / 8;
        src = wo; sstride = 512; r0 = by * 64; c0 = bx * 64;
        dst = wo_t; dstride = 512; dr0 = c0;
    } else if (b < 512) {     // w1: [512][2048] -> [2048][512]
        int tt = b - 256; int bx = tt % 32, by = tt / 32;
        src = w1; sstride = 2048; r0 = by * 64; c0 = bx * 64;
        dst = w1_t; dstride = 512; dr0 = c0;
    } else {                  // w2: [2048][512] -> [512][2048]
        int tt = b - 512; int bx = tt % 8, by = tt / 8;
        src = w2; sstride = 512; r0 = by * 64; c0 = bx * 64;
        dst = w2_t; dstride = 2048; dr0 = c0;
    }
    #pragma unroll
    for (int p = 0; p < 16; p++) {
        int lin = threadIdx.x + p * 256;
        int rr = lin >> 6, cc = lin & 63;
        t[rr][cc] = src[(size_t)(r0 + rr) * sstride + c0 + cc];
    }
    __syncthreads();
    #pragma unroll
    for (int p = 0; p < 16; p++) {
        int lin = threadIdx.x + p * 256;
        int cc = lin >> 6, rr = lin & 63;
        dst[(size_t)(dr0 + cc) * dstride + r0 + rr] = (bf16)t[rr][cc];
    }
}

// ---------------- layernorm: fp32 in, bf16 out (one wave per row of 512) ----------------
__global__ void ln_kernel(const float* __restrict__ x, const float* __restrict__ g,
                          const float* __restrict__ b, bf16* __restrict__ out) {
    int row = blockIdx.x * 4 + (threadIdx.x >> 6);
    int lane = threadIdx.x & 63;
    const float4* xr = (const float4*)(x + (size_t)row * 512);
    float4 v0 = xr[lane];
    float4 v1 = xr[lane + 64];
    float s  = v0.x + v0.y + v0.z + v0.w + v1.x + v1.y + v1.z + v1.w;
    float sq = v0.x*v0.x + v0.y*v0.y + v0.z*v0.z + v0.w*v0.w
             + v1.x*v1.x + v1.y*v1.y + v1.z*v1.z + v1.w*v1.w;
    #pragma unroll
    for (int d = 1; d < 64; d <<= 1) { s += __shfl_xor(s, d); sq += __shfl_xor(sq, d); }
    float mean = s * (1.f / 512.f);
    float var  = sq * (1.f / 512.f) - mean * mean;
    float rs   = rsqrtf(var + 1e-5f);
    const float4* gv = (const float4*)g;
    const float4* bv = (const float4*)b;
    float4 ga = gv[lane], gb = gv[lane + 64];
    float4 ba = bv[lane], bb = bv[lane + 64];
    bf16* orow = out + (size_t)row * 512;
    int c0 = lane * 4;
    orow[c0 + 0]   = (bf16)((v0.x - mean) * rs * ga.x + ba.x);
    orow[c0 + 1]   = (bf16)((v0.y - mean) * rs * ga.y + ba.y);
    orow[c0 + 2]   = (bf16)((v0.z - mean) * rs * ga.z + ba.z);
    orow[c0 + 3]   = (bf16)((v0.w - mean) * rs * ga.w + ba.w);
    orow[c0 + 256] = (bf16)((v1.x - mean) * rs * gb.x + bb.x);
    orow[c0 + 257] = (bf16)((v1.y - mean) * rs * gb.y + bb.y);
    orow[c0 + 258] = (bf16)((v1.z - mean) * rs * gb.z + bb.z);
    orow[c0 + 259] = (bf16)((v1.w - mean) * rs * gb.w + bb.w);
}

// ---------------- GEMM 128x128: C[M][ND] = A[M][KD] @ Bt[ND][KD]^T ----------------
// EPI: 0 = store bf16; 2 = +bias, SiLU -> bf16
template<int KD, int ND, int EPI>
__global__ __launch_bounds__(256, 3) void gemm_k(
        const bf16* __restrict__ A, const bf16* __restrict__ Bt,
        const float* __restrict__ bias, void* __restrict__ outp) {
    __shared__ bf16 As[128 * 64];
    __shared__ bf16 Bs[128 * 64];
    const int bm = blockIdx.x, bn = blockIdx.y;
    const int tid = threadIdx.x;
    const int w = tid >> 6, lane = tid & 63;
    const int wm = (w >> 1) * 64, wn = (w & 1) * 64;
    const int lr = lane & 15, lq = lane >> 4, lr7 = lane & 7;
    const int srow = lane >> 3, gslot = lane & 7;
    f32x4 acc[4][4] = {};
    const bf16* Ab = A + (size_t)bm * 128 * KD;
    const bf16* Bb = Bt + (size_t)bn * 128 * KD;
    const int gcol = (gslot ^ srow) * 8;
    for (int k0 = 0; k0 < KD; k0 += 64) {
        __syncthreads();
        #pragma unroll
        for (int s = 0; s < 4; s++) {
            int rbase = w * 32 + s * 8;
            int row = rbase + srow;
            load_lds16(&Ab[(size_t)row * KD + k0 + gcol], &As[rbase * 64]);
            load_lds16(&Bb[(size_t)row * KD + k0 + gcol], &Bs[rbase * 64]);
        }
        __syncthreads();
        #pragma unroll
        for (int ks = 0; ks < 2; ks++) {
            bf16x8 af[4], bfr[4];
            #pragma unroll
            for (int mi = 0; mi < 4; mi++) {
                int row = wm + mi * 16 + lr;
                af[mi] = *(const bf16x8*)&As[row * 64 + (((ks * 4 + lq) ^ lr7) << 3)];
            }
            #pragma unroll
            for (int ni = 0; ni < 4; ni++) {
                int row = wn + ni * 16 + lr;
                bfr[ni] = *(const bf16x8*)&Bs[row * 64 + (((ks * 4 + lq) ^ lr7) << 3)];
            }
            #pragma unroll
            for (int mi = 0; mi < 4; mi++)
                #pragma unroll
                for (int ni = 0; ni < 4; ni++)
                    acc[mi][ni] = MFMA16(af[mi], bfr[ni], acc[mi][ni]);
        }
    }
    #pragma unroll
    for (int mi = 0; mi < 4; mi++)
        #pragma unroll
        for (int ni = 0; ni < 4; ni++)
            #pragma unroll
            for (int r = 0; r < 4; r++) {
                int row = bm * 128 + wm + mi * 16 + lq * 4 + r;
                int col = bn * 128 + wn + ni * 16 + lr;
                float v = acc[mi][ni][r];
                size_t off = (size_t)row * ND + col;
                if constexpr (EPI == 0) {
                    ((bf16*)outp)[off] = (bf16)v;
                } else {
                    v += bias[col];
                    v = v / (1.f + __expf(-v));   // SiLU
                    ((bf16*)outp)[off] = (bf16)v;
                }
            }
}

// ---------------- GEMM 64x64 tiles for N=512 outputs (AO, FF2) ----------------
// out fp32 = A@Bt^T + bias + resid (R4-measured config)
template<int KD>
__global__ __launch_bounds__(256, 4) void gemm64(
        const bf16* __restrict__ A, const bf16* __restrict__ Bt,
        const float* __restrict__ bias, const float* __restrict__ resid,
        float* __restrict__ outp) {
    __shared__ bf16 As[64 * 64];
    __shared__ bf16 Bs[64 * 64];
    const int bm = blockIdx.x, bn = blockIdx.y;
    const int tid = threadIdx.x;
    const int w = tid >> 6, lane = tid & 63;
    const int wm = (w >> 1) * 32, wn = (w & 1) * 32;
    const int lr = lane & 15, lq = lane >> 4, lr7 = lane & 7;
    const int srow = lane >> 3, gslot = lane & 7;
    f32x4 acc[2][2] = {};
    const bf16* Ab = A + (size_t)bm * 64 * KD;
    const bf16* Bb = Bt + (size_t)bn * 64 * KD;
    const int gcol = (gslot ^ srow) * 8;
    for (int k0 = 0; k0 < KD; k0 += 64) {
        __syncthreads();
        #pragma unroll
        for (int s = 0; s < 2; s++) {
            int rbase = w * 16 + s * 8;
            int row = rbase + srow;
            load_lds16(&Ab[(size_t)row * KD + k0 + gcol], &As[rbase * 64]);
            load_lds16(&Bb[(size_t)row * KD + k0 + gcol], &Bs[rbase * 64]);
        }
        __syncthreads();
        #pragma unroll
        for (int ks = 0; ks < 2; ks++) {
            bf16x8 af[2], bfr[2];
            #pragma unroll
            for (int mi = 0; mi < 2; mi++) {
                int row = wm + mi * 16 + lr;
                af[mi] = *(const bf16x8*)&As[row * 64 + (((ks * 4 + lq) ^ lr7) << 3)];
            }
            #pragma unroll
            for (int ni = 0; ni < 2; ni++) {
                int row = wn + ni * 16 + lr;
                bfr[ni] = *(const bf16x8*)&Bs[row * 64 + (((ks * 4 + lq) ^ lr7) << 3)];
            }
            #pragma unroll
            for (int mi = 0; mi < 2; mi++)
                #pragma unroll
                for (int ni = 0; ni < 2; ni++)
                    acc[mi][ni] = MFMA16(af[mi], bfr[ni], acc[mi][ni]);
        }
    }
    #pragma unroll
    for (int mi = 0; mi < 2; mi++)
        #pragma unroll
        for (int ni = 0; ni < 2; ni++)
            #pragma unroll
            for (int r = 0; r < 4; r++) {
                int row = bm * 64 + wm + mi * 16 + lq * 4 + r;
                int col = bn * 64 + wn + ni * 16 + lr;
                size_t off = (size_t)row * 512 + col;
                outp[off] = acc[mi][ni][r] + bias[col] + resid[off];
            }
}

// ---------------- V transpose: qkvb V-part -> Vt[nh*64 + d][2048] ----------------
__global__ void vt_kernel(const bf16* __restrict__ qkvb, bf16* __restrict__ Vt) {
    __shared__ bf16 t[64 * 72];
    const int nh = blockIdx.x & 31, lt = blockIdx.x >> 5;
    const int n = nh >> 3, h = nh & 7;
    const int tid = threadIdx.x;
    #pragma unroll
    for (int p = 0; p < 2; p++) {
        int lin = tid + p * 256;
        int rr = lin >> 3, cc = lin & 7;          // token row, d-chunk
        bf16x8 v = *(const bf16x8*)&qkvb[(size_t)(n * 2048 + lt * 64 + rr) * 1536
                                         + 1024 + h * 64 + cc * 8];
        *(bf16x8*)&t[rr * 72 + (cc ^ (rr & 7)) * 8] = v;   // swizzled chunk
    }
    __syncthreads();
    #pragma unroll
    for (int p = 0; p < 2; p++) {
        int lin = tid + p * 256;
        int dd = lin & 63, llc = lin >> 6;        // d row, token chunk
        bf16x8 o;
        #pragma unroll
        for (int j = 0; j < 8; j++) {
            int ll = llc * 8 + j;
            o[j] = t[ll * 72 + (((dd >> 3) ^ (ll & 7)) * 8) + (dd & 7)];
        }
        *(bf16x8*)&Vt[(size_t)(nh * 64 + dd) * 2048 + lt * 64 + llc * 8] = o;
    }
}

// ---------------- flash attention: register-resident, 2-way K-split, prefetch ------
// 512 blocks (nh low 5 bits -> XCD L2 locality), 512 thr = 8 waves:
// qsub = w&3 (32 Q rows), ks = w>>2 (half the keys, 32 kb-blocks of 32 keys).
// St = K*Q^T via 32x32x16 MFMA; P -> PV B-layout via lane^32 half-swap (no LDS).
// Fixed-max softmax, unnormalized accumulate; K-split merged via LDS at the end.
// Next iteration's K/V prefetched into registers (no barriers in the loop).
__global__ __launch_bounds__(512, 4) void attn_kernel(const bf16* __restrict__ qkv,
                                                      const bf16* __restrict__ Vt,
                                                      bf16* __restrict__ aout) {
    __shared__ float accbuf[4][32][64];
    __shared__ float psumbuf[4][32];
    __shared__ bf16 Ot[4][32 * 72];
    const int b = blockIdx.x;
    const int nh = b & 31;             // low bits -> XCD locality
    const int qt = b >> 5;
    const int n = nh >> 3, h = nh & 7;
    const int tid = threadIdx.x, w = tid >> 6, lane = tid & 63;
    const int qsub = w & 3, ks = w >> 2;
    const int lq5 = lane & 31, g = lane >> 5;
    const float cf = 0.04419417382415922f * 1.4426950408889634f;  // 512^-0.5 * log2e

    // Q B-fragments (lane holds Q[q=lq5][d-chunk g*8], 4 chunks of k=16)
    const bf16* Qp = qkv + (size_t)(n * 2048 + qt * 128 + qsub * 32 + lq5) * 1536
                     + h * 64 + g * 8;
    bf16x8 qf[4];
    #pragma unroll
    for (int c = 0; c < 4; c++) {
        bf16x8 raw = *(const bf16x8*)(Qp + c * 16);
        #pragma unroll
        for (int j = 0; j < 8; j++) qf[c][j] = (bf16)((float)raw[j] * cf);
    }

    f32x16 acc0 = {0}, acc1 = {0};     // O^T C-frags: d-blocks 0..31, 32..63
    float psum = 0.f;

    const bf16* Kp = qkv + (size_t)(n * 2048 + ks * 1024 + lq5) * 1536
                     + 512 + h * 64 + g * 8;
    const bf16* Vp = Vt + (size_t)(nh * 64 + lq5) * 2048 + ks * 1024 + g * 8;

    bf16x8 kfn[4], vn00, vn01, vn10, vn11;
    {   // preload t = 0
        kfn[0] = *(const bf16x8*)(Kp);
        kfn[1] = *(const bf16x8*)(Kp + 16);
        kfn[2] = *(const bf16x8*)(Kp + 32);
        kfn[3] = *(const bf16x8*)(Kp + 48);
        vn00 = *(const bf16x8*)(Vp);
        vn01 = *(const bf16x8*)(Vp + (size_t)32 * 2048);
        vn10 = *(const bf16x8*)(Vp + 16);
        vn11 = *(const bf16x8*)(Vp + 16 + (size_t)32 * 2048);
    }

    #pragma unroll 4
    for (int t = 0; t < 32; t++) {
        bf16x8 kfc0 = kfn[0], kfc1 = kfn[1], kfc2 = kfn[2], kfc3 = kfn[3];
        bf16x8 v00 = vn00, v01 = vn01, v10 = vn10, v11 = vn11;
        if (t < 31) {                  // prefetch t+1 while computing t
            const bf16* Kt = Kp + (size_t)(t + 1) * 32 * 1536;
            const bf16* Vtp = Vp + (t + 1) * 32;
            kfn[0] = *(const bf16x8*)(Kt);
            kfn[1] = *(const bf16x8*)(Kt + 16);
            kfn[2] = *(const bf16x8*)(Kt + 32);
            kfn[3] = *(const bf16x8*)(Kt + 48);
            vn00 = *(const bf16x8*)(Vtp);
            vn01 = *(const bf16x8*)(Vtp + (size_t)32 * 2048);
            vn10 = *(const bf16x8*)(Vtp + 16);
            vn11 = *(const bf16x8*)(Vtp + 16 + (size_t)32 * 2048);
        }

        // St[key][q] (pre-scaled to log2 domain via Q)
        f32x16 st = {0};
        st = MFMA32(kfc0, qf[0], st);
        st = MFMA32(kfc1, qf[1], st);
        st = MFMA32(kfc2, qf[2], st);
        st = MFMA32(kfc3, qf[3], st);

        // p = exp2(min(s,60)); pack to bf16 pairs; per-lane psum
        uint32_t pk[8];
        #pragma unroll
        for (int i = 0; i < 8; i++) {
            float p0 = fexp2(fminf(st[2 * i], 60.f));
            float p1 = fexp2(fminf(st[2 * i + 1], 60.f));
            psum += p0 + p1;
            union { uint32_t u; bf16x2 h; } cvu;
            cvu.h = bf16x2{(bf16)p0, (bf16)p1};
            pk[i] = cvu.u;
        }
        // PV: B-frag(h16) built by lane^32 half-swap; A = V^T rows (registers)
        #pragma unroll
        for (int h16 = 0; h16 < 2; h16++) {
            uint32_t s0 = g ? pk[4 * h16]     : pk[4 * h16 + 2];
            uint32_t s1 = g ? pk[4 * h16 + 1] : pk[4 * h16 + 3];
            uint32_t r0 = (uint32_t)__shfl_xor((int)s0, 32);
            uint32_t r1 = (uint32_t)__shfl_xor((int)s1, 32);
            union { uint4 u; bf16x8 v; } pf;
            pf.u = g == 0 ? uint4{pk[4 * h16], pk[4 * h16 + 1], r0, r1}
                          : uint4{r0, r1, pk[4 * h16 + 2], pk[4 * h16 + 3]};
            if (h16 == 0) {
                acc0 = MFMA32(v00, pf.v, acc0);
                acc1 = MFMA32(v01, pf.v, acc1);
            } else {
                acc0 = MFMA32(v10, pf.v, acc0);
                acc1 = MFMA32(v11, pf.v, acc1);
            }
        }
    }

    // per-q total over this wave's half of the keys
    float tot = psum + __shfl_xor(psum, 32);

    // merge K-split halves via LDS (fixed-max softmax: plain sums, no rescale)
    if (ks == 1) {
        #pragma unroll
        for (int r = 0; r < 16; r++) {
            accbuf[qsub][r][lane]      = acc0[r];
            accbuf[qsub][16 + r][lane] = acc1[r];
        }
        if (g == 0) psumbuf[qsub][lq5] = tot;
    }
    __syncthreads();
    if (ks == 0) {
        float inv = 1.f / (tot + psumbuf[qsub][lq5]);
        bf16* ot = Ot[qsub];
        #pragma unroll
        for (int r = 0; r < 16; r++) {
            float a0 = acc0[r] + accbuf[qsub][r][lane];
            float a1 = acc1[r] + accbuf[qsub][16 + r][lane];
            int d0 = (r & 3) + 8 * (r >> 2) + 4 * g;
            ot[lq5 * 72 + d0]      = (bf16)(a0 * inv);
            ot[lq5 * 72 + d0 + 32] = (bf16)(a1 * inv);
        }
        __builtin_amdgcn_s_waitcnt(0);     // drain lgkm before same-wave readback
        #pragma unroll
        for (int i = 0; i < 4; i++) {
            int tq = i * 8 + (lane >> 3);
            bf16x8 ov = *(const bf16x8*)&ot[tq * 72 + (lane & 7) * 8];
            *(bf16x8*)&aout[(size_t)(n * 2048 + qt * 128 + qsub * 32 + tq) * 512
                            + h * 64 + (lane & 7) * 8] = ov;
        }
    }
}

extern "C" void kernel_launch(void* const* d_in, const int* in_sizes, int n_in,
                              void* d_out, int out_size, void* d_ws, size_t ws_size,
                              hipStream_t stream) {
    (void)in_sizes; (void)n_in; (void)out_size; (void)ws_size;
    const float* x   = (const float*)d_in[0];
    const float* wq  = (const float*)d_in[1];
    const float* wk  = (const float*)d_in[2];
    const float* wv  = (const float*)d_in[3];
    const float* wo  = (const float*)d_in[4];
    const float* bo  = (const float*)d_in[5];
    const float* g1  = (const float*)d_in[6];
    const float* b1  = (const float*)d_in[7];
    const float* g2  = (const float*)d_in[8];
    const float* b2  = (const float*)d_in[9];
    const float* w1  = (const float*)d_in[10];
    const float* bf1 = (const float*)d_in[11];
    const float* w2  = (const float*)d_in[12];
    const float* bf2 = (const float*)d_in[13];
    float* out = (float*)d_out;

    char* p = (char*)d_ws;
    bf16*  h1     = (bf16*)p;  p += (size_t)8192 * 512 * 2;    // LN out (reused)
    bf16*  qkvb   = (bf16*)p;  p += (size_t)8192 * 1536 * 2;   // packed Q|K|V
    bf16*  aout   = (bf16*)p;  p += (size_t)8192 * 512 * 2;    // attention out
    float* x2     = (float*)p; p += (size_t)8192 * 512 * 4;    // post-attn residual
    bf16*  ff1    = (bf16*)p;  p += (size_t)8192 * 2048 * 2;   // SiLU(h@w1+b)
    bf16*  wqkv_t = (bf16*)p;  p += (size_t)1536 * 512 * 2;
    bf16*  wo_t   = (bf16*)p;  p += (size_t)512 * 512 * 2;
    bf16*  w1_t   = (bf16*)p;  p += (size_t)2048 * 512 * 2;
    bf16*  w2_t   = (bf16*)p;  p += (size_t)512 * 2048 * 2;
    // Vt (8.4 MB) aliases the ff1 region: consumed by attn before FF1 writes ff1
    bf16*  Vt     = (bf16*)ff1;

    cvt_all<<<768, 256, 0, stream>>>(wq, wk, wv, wo, w1, w2, wqkv_t, wo_t, w1_t, w2_t);

    ln_kernel<<<2048, 256, 0, stream>>>(x, g1, b1, h1);
    gemm_k<512, 1536, 0><<<dim3(64, 12), 256, 0, stream>>>(h1, wqkv_t, nullptr, qkvb);
    vt_kernel<<<1024, 256, 0, stream>>>(qkvb, Vt);
    attn_kernel<<<512, 512, 0, stream>>>(qkvb, Vt, aout);
    gemm64<512><<<dim3(128, 8), 256, 0, stream>>>(aout, wo_t, bo, x, x2);
    ln_kernel<<<2048, 256, 0, stream>>>(x2, g2, b2, h1);
    gemm_k<512, 2048, 2><<<dim3(64, 16), 256, 0, stream>>>(h1, w1_t, bf1, ff1);
    gemm64<2048><<<dim3(128, 8), 256, 0, stream>>>(ff1, w2_t, bf2, x2, out);
}

// Round 7
// 302.961 us; speedup vs baseline: 1.4330x; 1.4330x over previous
//
#include <hip/hip_runtime.h>
#include <hip/hip_bf16.h>

typedef __bf16 bf16;
typedef __attribute__((ext_vector_type(2))) __bf16 bf16x2;
typedef __attribute__((ext_vector_type(8))) __bf16 bf16x8;
typedef __attribute__((ext_vector_type(4))) float f32x4;
typedef __attribute__((ext_vector_type(16))) float f32x16;

#define MFMA16(a, b, c) __builtin_amdgcn_mfma_f32_16x16x32_bf16((a), (b), (c), 0, 0, 0)
#define MFMA32(a, b, c) __builtin_amdgcn_mfma_f32_32x32x16_bf16((a), (b), (c), 0, 0, 0)

// Problem constants: N=4, L=2048, E=512, H=8, D=64, FF=2048, tokens = 8192.

__device__ __forceinline__ void load_lds16(const bf16* g, bf16* l) {
    __builtin_amdgcn_global_load_lds(
        (const __attribute__((address_space(1))) void*)g,
        (__attribute__((address_space(3))) void*)l, 16, 0, 0);
}

__device__ __forceinline__ float fexp2(float x) { return __builtin_amdgcn_exp2f(x); }

// ---------------- all weight transposes in ONE kernel (768 blocks) ----------------
__global__ void cvt_all(const float* __restrict__ wq, const float* __restrict__ wk,
                        const float* __restrict__ wv, const float* __restrict__ wo,
                        const float* __restrict__ w1, const float* __restrict__ w2,
                        bf16* __restrict__ wqkv_t, bf16* __restrict__ wo_t,
                        bf16* __restrict__ w1_t, bf16* __restrict__ w2_t) {
    __shared__ float t[64][65];
    const int b = blockIdx.x;
    const float* src; bf16* dst;
    int sstride, dstride, r0, c0, dr0;
    if (b < 192) {            // qkv: dst [1536][512]
        int bx = b % 24, by = b / 24;
        int j0 = bx * 64;
        src = (j0 < 512) ? wq : (j0 < 1024) ? wk : wv;
        sstride = 512; r0 = by * 64; c0 = j0 & 511;
        dst = wqkv_t; dstride = 512; dr0 = j0;
    } else if (b < 256) {     // wo
        int tt = b - 192; int bx = tt % 8, by = tt / 8;
        src = wo; sstride = 512; r0 = by * 64; c0 = bx * 64;
        dst = wo_t; dstride = 512; dr0 = c0;
    } else if (b < 512) {     // w1: [512][2048] -> [2048][512]
        int tt = b - 256; int bx = tt % 32, by = tt / 32;
        src = w1; sstride = 2048; r0 = by * 64; c0 = bx * 64;
        dst = w1_t; dstride = 512; dr0 = c0;
    } else {                  // w2: [2048][512] -> [512][2048]
        int tt = b - 512; int bx = tt % 8, by = tt / 8;
        src = w2; sstride = 512; r0 = by * 64; c0 = bx * 64;
        dst = w2_t; dstride = 2048; dr0 = c0;
    }
    #pragma unroll
    for (int p = 0; p < 16; p++) {
        int lin = threadIdx.x + p * 256;
        int rr = lin >> 6, cc = lin & 63;
        t[rr][cc] = src[(size_t)(r0 + rr) * sstride + c0 + cc];
    }
    __syncthreads();
    #pragma unroll
    for (int p = 0; p < 16; p++) {
        int lin = threadIdx.x + p * 256;
        int cc = lin >> 6, rr = lin & 63;
        dst[(size_t)(dr0 + cc) * dstride + r0 + rr] = (bf16)t[rr][cc];
    }
}

// ---------------- layernorm: fp32 in, bf16 out (one wave per row of 512) ----------------
__global__ void ln_kernel(const float* __restrict__ x, const float* __restrict__ g,
                          const float* __restrict__ b, bf16* __restrict__ out) {
    int row = blockIdx.x * 4 + (threadIdx.x >> 6);
    int lane = threadIdx.x & 63;
    const float4* xr = (const float4*)(x + (size_t)row * 512);
    float4 v0 = xr[lane];
    float4 v1 = xr[lane + 64];
    float s  = v0.x + v0.y + v0.z + v0.w + v1.x + v1.y + v1.z + v1.w;
    float sq = v0.x*v0.x + v0.y*v0.y + v0.z*v0.z + v0.w*v0.w
             + v1.x*v1.x + v1.y*v1.y + v1.z*v1.z + v1.w*v1.w;
    #pragma unroll
    for (int d = 1; d < 64; d <<= 1) { s += __shfl_xor(s, d); sq += __shfl_xor(sq, d); }
    float mean = s * (1.f / 512.f);
    float var  = sq * (1.f / 512.f) - mean * mean;
    float rs   = rsqrtf(var + 1e-5f);
    const float4* gv = (const float4*)g;
    const float4* bv = (const float4*)b;
    float4 ga = gv[lane], gb = gv[lane + 64];
    float4 ba = bv[lane], bb = bv[lane + 64];
    bf16* orow = out + (size_t)row * 512;
    int c0 = lane * 4;
    orow[c0 + 0]   = (bf16)((v0.x - mean) * rs * ga.x + ba.x);
    orow[c0 + 1]   = (bf16)((v0.y - mean) * rs * ga.y + ba.y);
    orow[c0 + 2]   = (bf16)((v0.z - mean) * rs * ga.z + ba.z);
    orow[c0 + 3]   = (bf16)((v0.w - mean) * rs * ga.w + ba.w);
    orow[c0 + 256] = (bf16)((v1.x - mean) * rs * gb.x + bb.x);
    orow[c0 + 257] = (bf16)((v1.y - mean) * rs * gb.y + bb.y);
    orow[c0 + 258] = (bf16)((v1.z - mean) * rs * gb.z + bb.z);
    orow[c0 + 259] = (bf16)((v1.w - mean) * rs * gb.w + bb.w);
}

// ---------------- GEMM 128x128: C[M][ND] = A[M][KD] @ Bt[ND][KD]^T ----------------
// EPI: 0 = store bf16; 2 = +bias, SiLU -> bf16
template<int KD, int ND, int EPI>
__global__ __launch_bounds__(256, 3) void gemm_k(
        const bf16* __restrict__ A, const bf16* __restrict__ Bt,
        const float* __restrict__ bias, void* __restrict__ outp) {
    __shared__ bf16 As[128 * 64];
    __shared__ bf16 Bs[128 * 64];
    const int bm = blockIdx.x, bn = blockIdx.y;
    const int tid = threadIdx.x;
    const int w = tid >> 6, lane = tid & 63;
    const int wm = (w >> 1) * 64, wn = (w & 1) * 64;
    const int lr = lane & 15, lq = lane >> 4, lr7 = lane & 7;
    const int srow = lane >> 3, gslot = lane & 7;
    f32x4 acc[4][4] = {};
    const bf16* Ab = A + (size_t)bm * 128 * KD;
    const bf16* Bb = Bt + (size_t)bn * 128 * KD;
    const int gcol = (gslot ^ srow) * 8;
    for (int k0 = 0; k0 < KD; k0 += 64) {
        __syncthreads();
        #pragma unroll
        for (int s = 0; s < 4; s++) {
            int rbase = w * 32 + s * 8;
            int row = rbase + srow;
            load_lds16(&Ab[(size_t)row * KD + k0 + gcol], &As[rbase * 64]);
            load_lds16(&Bb[(size_t)row * KD + k0 + gcol], &Bs[rbase * 64]);
        }
        __syncthreads();
        #pragma unroll
        for (int ks = 0; ks < 2; ks++) {
            bf16x8 af[4], bfr[4];
            #pragma unroll
            for (int mi = 0; mi < 4; mi++) {
                int row = wm + mi * 16 + lr;
                af[mi] = *(const bf16x8*)&As[row * 64 + (((ks * 4 + lq) ^ lr7) << 3)];
            }
            #pragma unroll
            for (int ni = 0; ni < 4; ni++) {
                int row = wn + ni * 16 + lr;
                bfr[ni] = *(const bf16x8*)&Bs[row * 64 + (((ks * 4 + lq) ^ lr7) << 3)];
            }
            #pragma unroll
            for (int mi = 0; mi < 4; mi++)
                #pragma unroll
                for (int ni = 0; ni < 4; ni++)
                    acc[mi][ni] = MFMA16(af[mi], bfr[ni], acc[mi][ni]);
        }
    }
    #pragma unroll
    for (int mi = 0; mi < 4; mi++)
        #pragma unroll
        for (int ni = 0; ni < 4; ni++)
            #pragma unroll
            for (int r = 0; r < 4; r++) {
                int row = bm * 128 + wm + mi * 16 + lq * 4 + r;
                int col = bn * 128 + wn + ni * 16 + lr;
                float v = acc[mi][ni][r];
                size_t off = (size_t)row * ND + col;
                if constexpr (EPI == 0) {
                    ((bf16*)outp)[off] = (bf16)v;
                } else {
                    v += bias[col];
                    v = v / (1.f + __expf(-v));   // SiLU
                    ((bf16*)outp)[off] = (bf16)v;
                }
            }
}

// ---------------- GEMM 64x64 tiles for N=512 outputs (AO, FF2) ----------------
// out fp32 = A@Bt^T + bias + resid (R4-measured config)
template<int KD>
__global__ __launch_bounds__(256, 4) void gemm64(
        const bf16* __restrict__ A, const bf16* __restrict__ Bt,
        const float* __restrict__ bias, const float* __restrict__ resid,
        float* __restrict__ outp) {
    __shared__ bf16 As[64 * 64];
    __shared__ bf16 Bs[64 * 64];
    const int bm = blockIdx.x, bn = blockIdx.y;
    const int tid = threadIdx.x;
    const int w = tid >> 6, lane = tid & 63;
    const int wm = (w >> 1) * 32, wn = (w & 1) * 32;
    const int lr = lane & 15, lq = lane >> 4, lr7 = lane & 7;
    const int srow = lane >> 3, gslot = lane & 7;
    f32x4 acc[2][2] = {};
    const bf16* Ab = A + (size_t)bm * 64 * KD;
    const bf16* Bb = Bt + (size_t)bn * 64 * KD;
    const int gcol = (gslot ^ srow) * 8;
    for (int k0 = 0; k0 < KD; k0 += 64) {
        __syncthreads();
        #pragma unroll
        for (int s = 0; s < 2; s++) {
            int rbase = w * 16 + s * 8;
            int row = rbase + srow;
            load_lds16(&Ab[(size_t)row * KD + k0 + gcol], &As[rbase * 64]);
            load_lds16(&Bb[(size_t)row * KD + k0 + gcol], &Bs[rbase * 64]);
        }
        __syncthreads();
        #pragma unroll
        for (int ks = 0; ks < 2; ks++) {
            bf16x8 af[2], bfr[2];
            #pragma unroll
            for (int mi = 0; mi < 2; mi++) {
                int row = wm + mi * 16 + lr;
                af[mi] = *(const bf16x8*)&As[row * 64 + (((ks * 4 + lq) ^ lr7) << 3)];
            }
            #pragma unroll
            for (int ni = 0; ni < 2; ni++) {
                int row = wn + ni * 16 + lr;
                bfr[ni] = *(const bf16x8*)&Bs[row * 64 + (((ks * 4 + lq) ^ lr7) << 3)];
            }
            #pragma unroll
            for (int mi = 0; mi < 2; mi++)
                #pragma unroll
                for (int ni = 0; ni < 2; ni++)
                    acc[mi][ni] = MFMA16(af[mi], bfr[ni], acc[mi][ni]);
        }
    }
    #pragma unroll
    for (int mi = 0; mi < 2; mi++)
        #pragma unroll
        for (int ni = 0; ni < 2; ni++)
            #pragma unroll
            for (int r = 0; r < 4; r++) {
                int row = bm * 64 + wm + mi * 16 + lq * 4 + r;
                int col = bn * 64 + wn + ni * 16 + lr;
                size_t off = (size_t)row * 512 + col;
                outp[off] = acc[mi][ni][r] + bias[col] + resid[off];
            }
}

// ---------------- V transpose: qkvb V-part -> Vt[nh*64 + d][2048] ----------------
__global__ void vt_kernel(const bf16* __restrict__ qkvb, bf16* __restrict__ Vt) {
    __shared__ bf16 t[64 * 72];
    const int nh = blockIdx.x & 31, lt = blockIdx.x >> 5;
    const int n = nh >> 3, h = nh & 7;
    const int tid = threadIdx.x;
    #pragma unroll
    for (int p = 0; p < 2; p++) {
        int lin = tid + p * 256;
        int rr = lin >> 3, cc = lin & 7;          // token row, d-chunk
        bf16x8 v = *(const bf16x8*)&qkvb[(size_t)(n * 2048 + lt * 64 + rr) * 1536
                                         + 1024 + h * 64 + cc * 8];
        *(bf16x8*)&t[rr * 72 + (cc ^ (rr & 7)) * 8] = v;   // swizzled chunk
    }
    __syncthreads();
    #pragma unroll
    for (int p = 0; p < 2; p++) {
        int lin = tid + p * 256;
        int dd = lin & 63, llc = lin >> 6;        // d row, token chunk
        bf16x8 o;
        #pragma unroll
        for (int j = 0; j < 8; j++) {
            int ll = llc * 8 + j;
            o[j] = t[ll * 72 + (((dd >> 3) ^ (ll & 7)) * 8) + (dd & 7)];
        }
        *(bf16x8*)&Vt[(size_t)(nh * 64 + dd) * 2048 + lt * 64 + llc * 8] = o;
    }
}

// ---------------- flash attention: register-resident, 2-way K-split ----------------
// 512 blocks (nh low 5 bits -> XCD L2 locality), 512 thr = 8 waves:
// qsub = w&3 (32 Q rows), ks = w>>2 (half the keys, 32 kb-blocks of 32 keys).
// St = K*Q^T via 32x32x16 MFMA; P -> PV B-layout via lane^32 half-swap (no LDS).
// Fixed-max softmax, unnormalized accumulate; K-split merged via LDS at the end.
// Register budget <=128 (2 blocks/CU): prefetch ONLY K across iterations (16 regs);
// V loads issue at the top of each iteration, covered by the S-MFMA + softmax.
__global__ __launch_bounds__(512, 4) void attn_kernel(const bf16* __restrict__ qkv,
                                                      const bf16* __restrict__ Vt,
                                                      bf16* __restrict__ aout) {
    __shared__ float accbuf[4][32][64];
    __shared__ float psumbuf[4][32];
    __shared__ bf16 Ot[4][32 * 72];
    const int b = blockIdx.x;
    const int nh = b & 31;             // low bits -> XCD locality
    const int qt = b >> 5;
    const int n = nh >> 3, h = nh & 7;
    const int tid = threadIdx.x, w = tid >> 6, lane = tid & 63;
    const int qsub = w & 3, ks = w >> 2;
    const int lq5 = lane & 31, g = lane >> 5;
    const float cf = 0.04419417382415922f * 1.4426950408889634f;  // 512^-0.5 * log2e

    // Q B-fragments (lane holds Q[q=lq5][d-chunk g*8], 4 chunks of k=16)
    const bf16* Qp = qkv + (size_t)(n * 2048 + qt * 128 + qsub * 32 + lq5) * 1536
                     + h * 64 + g * 8;
    bf16x8 qf[4];
    #pragma unroll
    for (int c = 0; c < 4; c++) {
        bf16x8 raw = *(const bf16x8*)(Qp + c * 16);
        #pragma unroll
        for (int j = 0; j < 8; j++) qf[c][j] = (bf16)((float)raw[j] * cf);
    }

    f32x16 acc0 = {0}, acc1 = {0};     // O^T C-frags: d-blocks 0..31, 32..63
    float psum = 0.f;

    const bf16* Kp = qkv + (size_t)(n * 2048 + ks * 1024 + lq5) * 1536
                     + 512 + h * 64 + g * 8;
    const bf16* Vp = Vt + (size_t)(nh * 64 + lq5) * 2048 + ks * 1024 + g * 8;

    bf16x8 kfn[4];                     // K prefetch (the only cross-iter regs)
    kfn[0] = *(const bf16x8*)(Kp);
    kfn[1] = *(const bf16x8*)(Kp + 16);
    kfn[2] = *(const bf16x8*)(Kp + 32);
    kfn[3] = *(const bf16x8*)(Kp + 48);

    #pragma unroll 2
    for (int t = 0; t < 32; t++) {
        // V loads for THIS iteration: latency covered by S-MFMAs + softmax below
        const bf16* Vc = Vp + t * 32;
        bf16x8 v00 = *(const bf16x8*)(Vc);
        bf16x8 v01 = *(const bf16x8*)(Vc + (size_t)32 * 2048);
        bf16x8 v10 = *(const bf16x8*)(Vc + 16);
        bf16x8 v11 = *(const bf16x8*)(Vc + 16 + (size_t)32 * 2048);

        // St[key][q] (pre-scaled to log2 domain via Q)
        f32x16 st = {0};
        st = MFMA32(kfn[0], qf[0], st);
        st = MFMA32(kfn[1], qf[1], st);
        st = MFMA32(kfn[2], qf[2], st);
        st = MFMA32(kfn[3], qf[3], st);

        if (t < 31) {                  // K prefetch for t+1 (after kfn consumed)
            const bf16* Kt = Kp + (size_t)(t + 1) * 32 * 1536;
            kfn[0] = *(const bf16x8*)(Kt);
            kfn[1] = *(const bf16x8*)(Kt + 16);
            kfn[2] = *(const bf16x8*)(Kt + 32);
            kfn[3] = *(const bf16x8*)(Kt + 48);
        }

        // softmax + pack + PV, in two 16-key halves (short pk liveness)
        #pragma unroll
        for (int h16 = 0; h16 < 2; h16++) {
            uint32_t pk[4];
            #pragma unroll
            for (int i = 0; i < 4; i++) {
                float p0 = fexp2(fminf(st[8 * h16 + 2 * i], 60.f));
                float p1 = fexp2(fminf(st[8 * h16 + 2 * i + 1], 60.f));
                psum += p0 + p1;
                union { uint32_t u; bf16x2 hh; } cvu;
                cvu.hh = bf16x2{(bf16)p0, (bf16)p1};
                pk[i] = cvu.u;
            }
            uint32_t s0 = g ? pk[0] : pk[2];
            uint32_t s1 = g ? pk[1] : pk[3];
            uint32_t r0 = (uint32_t)__shfl_xor((int)s0, 32);
            uint32_t r1 = (uint32_t)__shfl_xor((int)s1, 32);
            union { uint4 u; bf16x8 v; } pf;
            pf.u = g == 0 ? uint4{pk[0], pk[1], r0, r1}
                          : uint4{r0, r1, pk[2], pk[3]};
            if (h16 == 0) {
                acc0 = MFMA32(v00, pf.v, acc0);
                acc1 = MFMA32(v01, pf.v, acc1);
            } else {
                acc0 = MFMA32(v10, pf.v, acc0);
                acc1 = MFMA32(v11, pf.v, acc1);
            }
        }
    }

    // per-q total over this wave's half of the keys
    float tot = psum + __shfl_xor(psum, 32);

    // merge K-split halves via LDS (fixed-max softmax: plain sums, no rescale)
    if (ks == 1) {
        #pragma unroll
        for (int r = 0; r < 16; r++) {
            accbuf[qsub][r][lane]      = acc0[r];
            accbuf[qsub][16 + r][lane] = acc1[r];
        }
        if (g == 0) psumbuf[qsub][lq5] = tot;
    }
    __syncthreads();
    if (ks == 0) {
        float inv = 1.f / (tot + psumbuf[qsub][lq5]);
        bf16* ot = Ot[qsub];
        #pragma unroll
        for (int r = 0; r < 16; r++) {
            float a0 = acc0[r] + accbuf[qsub][r][lane];
            float a1 = acc1[r] + accbuf[qsub][16 + r][lane];
            int d0 = (r & 3) + 8 * (r >> 2) + 4 * g;
            ot[lq5 * 72 + d0]      = (bf16)(a0 * inv);
            ot[lq5 * 72 + d0 + 32] = (bf16)(a1 * inv);
        }
        __builtin_amdgcn_s_waitcnt(0);     // drain lgkm before same-wave readback
        #pragma unroll
        for (int i = 0; i < 4; i++) {
            int tq = i * 8 + (lane >> 3);
            bf16x8 ov = *(const bf16x8*)&ot[tq * 72 + (lane & 7) * 8];
            *(bf16x8*)&aout[(size_t)(n * 2048 + qt * 128 + qsub * 32 + tq) * 512
                            + h * 64 + (lane & 7) * 8] = ov;
        }
    }
}

extern "C" void kernel_launch(void* const* d_in, const int* in_sizes, int n_in,
                              void* d_out, int out_size, void* d_ws, size_t ws_size,
                              hipStream_t stream) {
    (void)in_sizes; (void)n_in; (void)out_size; (void)ws_size;
    const float* x   = (const float*)d_in[0];
    const float* wq  = (const float*)d_in[1];
    const float* wk  = (const float*)d_in[2];
    const float* wv  = (const float*)d_in[3];
    const float* wo  = (const float*)d_in[4];
    const float* bo  = (const float*)d_in[5];
    const float* g1  = (const float*)d_in[6];
    const float* b1  = (const float*)d_in[7];
    const float* g2  = (const float*)d_in[8];
    const float* b2  = (const float*)d_in[9];
    const float* w1  = (const float*)d_in[10];
    const float* bf1 = (const float*)d_in[11];
    const float* w2  = (const float*)d_in[12];
    const float* bf2 = (const float*)d_in[13];
    float* out = (float*)d_out;

    char* p = (char*)d_ws;
    bf16*  h1     = (bf16*)p;  p += (size_t)8192 * 512 * 2;    // LN out (reused)
    bf16*  qkvb   = (bf16*)p;  p += (size_t)8192 * 1536 * 2;   // packed Q|K|V
    bf16*  aout   = (bf16*)p;  p += (size_t)8192 * 512 * 2;    // attention out
    float* x2     = (float*)p; p += (size_t)8192 * 512 * 4;    // post-attn residual
    bf16*  ff1    = (bf16*)p;  p += (size_t)8192 * 2048 * 2;   // SiLU(h@w1+b)
    bf16*  wqkv_t = (bf16*)p;  p += (size_t)1536 * 512 * 2;
    bf16*  wo_t   = (bf16*)p;  p += (size_t)512 * 512 * 2;
    bf16*  w1_t   = (bf16*)p;  p += (size_t)2048 * 512 * 2;
    bf16*  w2_t   = (bf16*)p;  p += (size_t)512 * 2048 * 2;
    // Vt (8.4 MB) aliases the ff1 region: consumed by attn before FF1 writes ff1
    bf16*  Vt     = (bf16*)ff1;

    cvt_all<<<768, 256, 0, stream>>>(wq, wk, wv, wo, w1, w2, wqkv_t, wo_t, w1_t, w2_t);

    ln_kernel<<<2048, 256, 0, stream>>>(x, g1, b1, h1);
    gemm_k<512, 1536, 0><<<dim3(64, 12), 256, 0, stream>>>(h1, wqkv_t, nullptr, qkvb);
    vt_kernel<<<1024, 256, 0, stream>>>(qkvb, Vt);
    attn_kernel<<<512, 512, 0, stream>>>(qkvb, Vt, aout);
    gemm64<512><<<dim3(128, 8), 256, 0, stream>>>(aout, wo_t, bo, x, x2);
    ln_kernel<<<2048, 256, 0, stream>>>(x2, g2, b2, h1);
    gemm_k<512, 2048, 2><<<dim3(64, 16), 256, 0, stream>>>(h1, w1_t, bf1, ff1);
    gemm64<2048><<<dim3(128, 8), 256, 0, stream>>>(ff1, w2_t, bf2, x2, out);
}

// Round 8
// 243.686 us; speedup vs baseline: 1.7815x; 1.2432x over previous
//
#include <hip/hip_runtime.h>
#include <hip/hip_bf16.h>

typedef __bf16 bf16;
typedef __attribute__((ext_vector_type(2))) __bf16 bf16x2;
typedef __attribute__((ext_vector_type(8))) __bf16 bf16x8;
typedef __attribute__((ext_vector_type(4))) float f32x4;
typedef __attribute__((ext_vector_type(16))) float f32x16;

#define MFMA16(a, b, c) __builtin_amdgcn_mfma_f32_16x16x32_bf16((a), (b), (c), 0, 0, 0)
#define MFMA32(a, b, c) __builtin_amdgcn_mfma_f32_32x32x16_bf16((a), (b), (c), 0, 0, 0)

// Problem constants: N=4, L=2048, E=512, H=8, D=64, FF=2048, tokens = 8192.

__device__ __forceinline__ void load_lds16(const bf16* g, bf16* l) {
    __builtin_amdgcn_global_load_lds(
        (const __attribute__((address_space(1))) void*)g,
        (__attribute__((address_space(3))) void*)l, 16, 0, 0);
}

__device__ __forceinline__ float fexp2(float x) { return __builtin_amdgcn_exp2f(x); }

// ---------------- all weight transposes in ONE kernel (768 blocks) ----------------
__global__ void cvt_all(const float* __restrict__ wq, const float* __restrict__ wk,
                        const float* __restrict__ wv, const float* __restrict__ wo,
                        const float* __restrict__ w1, const float* __restrict__ w2,
                        bf16* __restrict__ wqkv_t, bf16* __restrict__ wo_t,
                        bf16* __restrict__ w1_t, bf16* __restrict__ w2_t) {
    __shared__ float t[64][65];
    const int b = blockIdx.x;
    const float* src; bf16* dst;
    int sstride, dstride, r0, c0, dr0;
    if (b < 192) {            // qkv: dst [1536][512]
        int bx = b % 24, by = b / 24;
        int j0 = bx * 64;
        src = (j0 < 512) ? wq : (j0 < 1024) ? wk : wv;
        sstride = 512; r0 = by * 64; c0 = j0 & 511;
        dst = wqkv_t; dstride = 512; dr0 = j0;
    } else if (b < 256) {     // wo
        int tt = b - 192; int bx = tt % 8, by = tt / 8;
        src = wo; sstride = 512; r0 = by * 64; c0 = bx * 64;
        dst = wo_t; dstride = 512; dr0 = c0;
    } else if (b < 512) {     // w1: [512][2048] -> [2048][512]
        int tt = b - 256; int bx = tt % 32, by = tt / 32;
        src = w1; sstride = 2048; r0 = by * 64; c0 = bx * 64;
        dst = w1_t; dstride = 512; dr0 = c0;
    } else {                  // w2: [2048][512] -> [512][2048]
        int tt = b - 512; int bx = tt % 8, by = tt / 8;
        src = w2; sstride = 512; r0 = by * 64; c0 = bx * 64;
        dst = w2_t; dstride = 2048; dr0 = c0;
    }
    #pragma unroll
    for (int p = 0; p < 16; p++) {
        int lin = threadIdx.x + p * 256;
        int rr = lin >> 6, cc = lin & 63;
        t[rr][cc] = src[(size_t)(r0 + rr) * sstride + c0 + cc];
    }
    __syncthreads();
    #pragma unroll
    for (int p = 0; p < 16; p++) {
        int lin = threadIdx.x + p * 256;
        int cc = lin >> 6, rr = lin & 63;
        dst[(size_t)(dr0 + cc) * dstride + r0 + rr] = (bf16)t[rr][cc];
    }
}

// ---------------- layernorm: fp32 in, bf16 out (one wave per row of 512) ----------------
__global__ void ln_kernel(const float* __restrict__ x, const float* __restrict__ g,
                          const float* __restrict__ b, bf16* __restrict__ out) {
    int row = blockIdx.x * 4 + (threadIdx.x >> 6);
    int lane = threadIdx.x & 63;
    const float4* xr = (const float4*)(x + (size_t)row * 512);
    float4 v0 = xr[lane];
    float4 v1 = xr[lane + 64];
    float s  = v0.x + v0.y + v0.z + v0.w + v1.x + v1.y + v1.z + v1.w;
    float sq = v0.x*v0.x + v0.y*v0.y + v0.z*v0.z + v0.w*v0.w
             + v1.x*v1.x + v1.y*v1.y + v1.z*v1.z + v1.w*v1.w;
    #pragma unroll
    for (int d = 1; d < 64; d <<= 1) { s += __shfl_xor(s, d); sq += __shfl_xor(sq, d); }
    float mean = s * (1.f / 512.f);
    float var  = sq * (1.f / 512.f) - mean * mean;
    float rs   = rsqrtf(var + 1e-5f);
    const float4* gv = (const float4*)g;
    const float4* bv = (const float4*)b;
    float4 ga = gv[lane], gb = gv[lane + 64];
    float4 ba = bv[lane], bb = bv[lane + 64];
    bf16* orow = out + (size_t)row * 512;
    int c0 = lane * 4;
    orow[c0 + 0]   = (bf16)((v0.x - mean) * rs * ga.x + ba.x);
    orow[c0 + 1]   = (bf16)((v0.y - mean) * rs * ga.y + ba.y);
    orow[c0 + 2]   = (bf16)((v0.z - mean) * rs * ga.z + ba.z);
    orow[c0 + 3]   = (bf16)((v0.w - mean) * rs * ga.w + ba.w);
    orow[c0 + 256] = (bf16)((v1.x - mean) * rs * gb.x + bb.x);
    orow[c0 + 257] = (bf16)((v1.y - mean) * rs * gb.y + bb.y);
    orow[c0 + 258] = (bf16)((v1.z - mean) * rs * gb.z + bb.z);
    orow[c0 + 259] = (bf16)((v1.w - mean) * rs * gb.w + bb.w);
}

// ---------------- GEMM 128x128: C[M][ND] = A[M][KD] @ Bt[ND][KD]^T ----------------
// EPI: 0 = store bf16; 2 = +bias, SiLU -> bf16
template<int KD, int ND, int EPI>
__global__ __launch_bounds__(256, 3) void gemm_k(
        const bf16* __restrict__ A, const bf16* __restrict__ Bt,
        const float* __restrict__ bias, void* __restrict__ outp) {
    __shared__ bf16 As[128 * 64];
    __shared__ bf16 Bs[128 * 64];
    const int bm = blockIdx.x, bn = blockIdx.y;
    const int tid = threadIdx.x;
    const int w = tid >> 6, lane = tid & 63;
    const int wm = (w >> 1) * 64, wn = (w & 1) * 64;
    const int lr = lane & 15, lq = lane >> 4, lr7 = lane & 7;
    const int srow = lane >> 3, gslot = lane & 7;
    f32x4 acc[4][4] = {};
    const bf16* Ab = A + (size_t)bm * 128 * KD;
    const bf16* Bb = Bt + (size_t)bn * 128 * KD;
    const int gcol = (gslot ^ srow) * 8;
    for (int k0 = 0; k0 < KD; k0 += 64) {
        __syncthreads();
        #pragma unroll
        for (int s = 0; s < 4; s++) {
            int rbase = w * 32 + s * 8;
            int row = rbase + srow;
            load_lds16(&Ab[(size_t)row * KD + k0 + gcol], &As[rbase * 64]);
            load_lds16(&Bb[(size_t)row * KD + k0 + gcol], &Bs[rbase * 64]);
        }
        __syncthreads();
        #pragma unroll
        for (int ks = 0; ks < 2; ks++) {
            bf16x8 af[4], bfr[4];
            #pragma unroll
            for (int mi = 0; mi < 4; mi++) {
                int row = wm + mi * 16 + lr;
                af[mi] = *(const bf16x8*)&As[row * 64 + (((ks * 4 + lq) ^ lr7) << 3)];
            }
            #pragma unroll
            for (int ni = 0; ni < 4; ni++) {
                int row = wn + ni * 16 + lr;
                bfr[ni] = *(const bf16x8*)&Bs[row * 64 + (((ks * 4 + lq) ^ lr7) << 3)];
            }
            #pragma unroll
            for (int mi = 0; mi < 4; mi++)
                #pragma unroll
                for (int ni = 0; ni < 4; ni++)
                    acc[mi][ni] = MFMA16(af[mi], bfr[ni], acc[mi][ni]);
        }
    }
    #pragma unroll
    for (int mi = 0; mi < 4; mi++)
        #pragma unroll
        for (int ni = 0; ni < 4; ni++)
            #pragma unroll
            for (int r = 0; r < 4; r++) {
                int row = bm * 128 + wm + mi * 16 + lq * 4 + r;
                int col = bn * 128 + wn + ni * 16 + lr;
                float v = acc[mi][ni][r];
                size_t off = (size_t)row * ND + col;
                if constexpr (EPI == 0) {
                    ((bf16*)outp)[off] = (bf16)v;
                } else {
                    v += bias[col];
                    v = v / (1.f + __expf(-v));   // SiLU
                    ((bf16*)outp)[off] = (bf16)v;
                }
            }
}

// ---------------- GEMM 64x64 tiles for N=512 outputs (AO, FF2) ----------------
// out fp32 = A@Bt^T + bias + resid (R4-measured config)
template<int KD>
__global__ __launch_bounds__(256, 4) void gemm64(
        const bf16* __restrict__ A, const bf16* __restrict__ Bt,
        const float* __restrict__ bias, const float* __restrict__ resid,
        float* __restrict__ outp) {
    __shared__ bf16 As[64 * 64];
    __shared__ bf16 Bs[64 * 64];
    const int bm = blockIdx.x, bn = blockIdx.y;
    const int tid = threadIdx.x;
    const int w = tid >> 6, lane = tid & 63;
    const int wm = (w >> 1) * 32, wn = (w & 1) * 32;
    const int lr = lane & 15, lq = lane >> 4, lr7 = lane & 7;
    const int srow = lane >> 3, gslot = lane & 7;
    f32x4 acc[2][2] = {};
    const bf16* Ab = A + (size_t)bm * 64 * KD;
    const bf16* Bb = Bt + (size_t)bn * 64 * KD;
    const int gcol = (gslot ^ srow) * 8;
    for (int k0 = 0; k0 < KD; k0 += 64) {
        __syncthreads();
        #pragma unroll
        for (int s = 0; s < 2; s++) {
            int rbase = w * 16 + s * 8;
            int row = rbase + srow;
            load_lds16(&Ab[(size_t)row * KD + k0 + gcol], &As[rbase * 64]);
            load_lds16(&Bb[(size_t)row * KD + k0 + gcol], &Bs[rbase * 64]);
        }
        __syncthreads();
        #pragma unroll
        for (int ks = 0; ks < 2; ks++) {
            bf16x8 af[2], bfr[2];
            #pragma unroll
            for (int mi = 0; mi < 2; mi++) {
                int row = wm + mi * 16 + lr;
                af[mi] = *(const bf16x8*)&As[row * 64 + (((ks * 4 + lq) ^ lr7) << 3)];
            }
            #pragma unroll
            for (int ni = 0; ni < 2; ni++) {
                int row = wn + ni * 16 + lr;
                bfr[ni] = *(const bf16x8*)&Bs[row * 64 + (((ks * 4 + lq) ^ lr7) << 3)];
            }
            #pragma unroll
            for (int mi = 0; mi < 2; mi++)
                #pragma unroll
                for (int ni = 0; ni < 2; ni++)
                    acc[mi][ni] = MFMA16(af[mi], bfr[ni], acc[mi][ni]);
        }
    }
    #pragma unroll
    for (int mi = 0; mi < 2; mi++)
        #pragma unroll
        for (int ni = 0; ni < 2; ni++)
            #pragma unroll
            for (int r = 0; r < 4; r++) {
                int row = bm * 64 + wm + mi * 16 + lq * 4 + r;
                int col = bn * 64 + wn + ni * 16 + lr;
                size_t off = (size_t)row * 512 + col;
                outp[off] = acc[mi][ni][r] + bias[col] + resid[off];
            }
}

// ---------------- pack K and V into MFMA-fragment-coalesced layouts ----------------
// Kfrag[((nh*64+kb)*4 + c)*64 + lane]*8 : lane=g*32+l5 holds K[kb*32+l5][c*16+g*8..+8]
// Vfrag[((nh*64+kb)*4 + r)*64 + lane]*8 : r={key<16?0:2}+{d>=32}, lane=((key>>3)&1)*32+(d&31),
//   element j = V^T[d][kb*32 + (r&2)*8 + (lane>>5)*8 + j]
// grid 1024 = (lt<<5)|nh (nh low bits -> same XCD as the attn consumers)
__global__ void pack_kv(const bf16* __restrict__ qkvb, bf16* __restrict__ Kfrag,
                        bf16* __restrict__ Vfrag) {
    __shared__ bf16 t[64 * 72];
    const int nh = blockIdx.x & 31, lt = blockIdx.x >> 5;
    const int n = nh >> 3, h = nh & 7;
    const int tid = threadIdx.x;
    // ---- K: per-thread 16B slice is contiguous in qkvb; fragment reindex on write
    #pragma unroll
    for (int p = 0; p < 2; p++) {
        int cid = tid + p * 256;
        int key = lt * 64 + (cid >> 3);
        int dc = cid & 7;                 // d = dc*8 .. +8
        bf16x8 kv = *(const bf16x8*)&qkvb[(size_t)(n * 2048 + key) * 1536
                                          + 512 + h * 64 + dc * 8];
        int kb = key >> 5, l5 = key & 31;
        int c = dc >> 1, g = dc & 1;
        *(bf16x8*)&Kfrag[(size_t)(((nh * 64 + kb) * 4 + c) * 64 + g * 32 + l5) * 8] = kv;
    }
    // ---- V: coalesced read -> swizzled LDS transpose -> fragment write
    #pragma unroll
    for (int p = 0; p < 2; p++) {
        int lin = tid + p * 256;
        int rr = lin >> 3, cc = lin & 7;          // token row, d-chunk
        bf16x8 v = *(const bf16x8*)&qkvb[(size_t)(n * 2048 + lt * 64 + rr) * 1536
                                         + 1024 + h * 64 + cc * 8];
        *(bf16x8*)&t[rr * 72 + (cc ^ (rr & 7)) * 8] = v;
    }
    __syncthreads();
    #pragma unroll
    for (int p = 0; p < 2; p++) {
        int lin = tid + p * 256;
        int dd = lin & 63, llc = lin >> 6 | (p << 2);   // d row, token chunk 0..7
        bf16x8 o;
        #pragma unroll
        for (int j = 0; j < 8; j++) {
            int ll = llc * 8 + j;
            o[j] = t[ll * 72 + (((dd >> 3) ^ (ll & 7)) * 8) + (dd & 7)];
        }
        int token0 = lt * 64 + llc * 8;
        int kb = token0 >> 5;
        int tl5 = token0 & 31;
        int r = ((tl5 >> 4) << 1) | (dd >> 5);
        int lane = ((token0 >> 3) & 1) * 32 + (dd & 31);
        *(bf16x8*)&Vfrag[(size_t)(((nh * 64 + kb) * 4 + r) * 64 + lane) * 8] = o;
    }
}

// ---------------- flash attention: register-resident, 2-way K-split, frag-packed ---
// 512 blocks (nh low 5 bits -> XCD L2 locality), 512 thr = 8 waves:
// qsub = w&3 (32 Q rows), ks = w>>2 (half the keys, 32 kb-blocks of 32 keys).
// All inner-loop K/V loads are base + lane*16B -> fully coalesced 1KB streams.
// St = K*Q^T via 32x32x16 MFMA; P -> PV B-layout via lane^32 half-swap (no LDS).
// Fixed-max softmax, unnormalized accumulate; K-split merged via LDS at the end.
__global__ __launch_bounds__(512, 4) void attn_kernel(const bf16* __restrict__ qkv,
                                                      const bf16* __restrict__ Kfrag,
                                                      const bf16* __restrict__ Vfrag,
                                                      bf16* __restrict__ aout) {
    __shared__ float accbuf[4][32][64];
    __shared__ float psumbuf[4][32];
    __shared__ bf16 Ot[4][32 * 72];
    const int b = blockIdx.x;
    const int nh = b & 31;             // low bits -> XCD locality
    const int qt = b >> 5;
    const int n = nh >> 3, h = nh & 7;
    const int tid = threadIdx.x, w = tid >> 6, lane = tid & 63;
    const int qsub = w & 3, ks = w >> 2;
    const int lq5 = lane & 31, g = lane >> 5;
    const float cf = 0.04419417382415922f * 1.4426950408889634f;  // 512^-0.5 * log2e

    // Q B-fragments (read once; strided is fine here)
    const bf16* Qp = qkv + (size_t)(n * 2048 + qt * 128 + qsub * 32 + lq5) * 1536
                     + h * 64 + g * 8;
    bf16x8 qf[4];
    #pragma unroll
    for (int c = 0; c < 4; c++) {
        bf16x8 raw = *(const bf16x8*)(Qp + c * 16);
        #pragma unroll
        for (int j = 0; j < 8; j++) qf[c][j] = (bf16)((float)raw[j] * cf);
    }

    f32x16 acc0 = {0}, acc1 = {0};     // O^T C-frags: d-blocks 0..31, 32..63
    float psum = 0.f;

    // fragment streams: element offset ((nh*64+kb)*4 + c)*512 + lane*8
    const bf16* Kb = Kfrag + (size_t)((nh * 64 + ks * 32) * 4) * 512 + lane * 8;
    const bf16* Vb = Vfrag + (size_t)((nh * 64 + ks * 32) * 4) * 512 + lane * 8;

    bf16x8 kfn[4];                     // K prefetch (the only cross-iter regs)
    kfn[0] = *(const bf16x8*)(Kb);
    kfn[1] = *(const bf16x8*)(Kb + 512);
    kfn[2] = *(const bf16x8*)(Kb + 1024);
    kfn[3] = *(const bf16x8*)(Kb + 1536);

    #pragma unroll 2
    for (int t = 0; t < 32; t++) {
        // V loads for THIS iteration (coalesced); covered by S-MFMAs + softmax
        const bf16* Vc = Vb + t * 2048;
        bf16x8 v00 = *(const bf16x8*)(Vc);
        bf16x8 v01 = *(const bf16x8*)(Vc + 512);
        bf16x8 v10 = *(const bf16x8*)(Vc + 1024);
        bf16x8 v11 = *(const bf16x8*)(Vc + 1536);

        // St[key][q] (pre-scaled to log2 domain via Q)
        f32x16 st = {0};
        st = MFMA32(kfn[0], qf[0], st);
        st = MFMA32(kfn[1], qf[1], st);
        st = MFMA32(kfn[2], qf[2], st);
        st = MFMA32(kfn[3], qf[3], st);

        if (t < 31) {                  // K prefetch for t+1 (coalesced)
            const bf16* Kt = Kb + (t + 1) * 2048;
            kfn[0] = *(const bf16x8*)(Kt);
            kfn[1] = *(const bf16x8*)(Kt + 512);
            kfn[2] = *(const bf16x8*)(Kt + 1024);
            kfn[3] = *(const bf16x8*)(Kt + 1536);
        }

        // softmax + pack + PV, in two 16-key halves (short pk liveness)
        #pragma unroll
        for (int h16 = 0; h16 < 2; h16++) {
            uint32_t pk[4];
            #pragma unroll
            for (int i = 0; i < 4; i++) {
                float p0 = fexp2(fminf(st[8 * h16 + 2 * i], 60.f));
                float p1 = fexp2(fminf(st[8 * h16 + 2 * i + 1], 60.f));
                psum += p0 + p1;
                union { uint32_t u; bf16x2 hh; } cvu;
                cvu.hh = bf16x2{(bf16)p0, (bf16)p1};
                pk[i] = cvu.u;
            }
            uint32_t s0 = g ? pk[0] : pk[2];
            uint32_t s1 = g ? pk[1] : pk[3];
            uint32_t r0 = (uint32_t)__shfl_xor((int)s0, 32);
            uint32_t r1 = (uint32_t)__shfl_xor((int)s1, 32);
            union { uint4 u; bf16x8 v; } pf;
            pf.u = g == 0 ? uint4{pk[0], pk[1], r0, r1}
                          : uint4{r0, r1, pk[2], pk[3]};
            if (h16 == 0) {
                acc0 = MFMA32(v00, pf.v, acc0);
                acc1 = MFMA32(v01, pf.v, acc1);
            } else {
                acc0 = MFMA32(v10, pf.v, acc0);
                acc1 = MFMA32(v11, pf.v, acc1);
            }
        }
    }

    // per-q total over this wave's half of the keys
    float tot = psum + __shfl_xor(psum, 32);

    // merge K-split halves via LDS (fixed-max softmax: plain sums, no rescale)
    if (ks == 1) {
        #pragma unroll
        for (int r = 0; r < 16; r++) {
            accbuf[qsub][r][lane]      = acc0[r];
            accbuf[qsub][16 + r][lane] = acc1[r];
        }
        if (g == 0) psumbuf[qsub][lq5] = tot;
    }
    __syncthreads();
    if (ks == 0) {
        float inv = 1.f / (tot + psumbuf[qsub][lq5]);
        bf16* ot = Ot[qsub];
        #pragma unroll
        for (int r = 0; r < 16; r++) {
            float a0 = acc0[r] + accbuf[qsub][r][lane];
            float a1 = acc1[r] + accbuf[qsub][16 + r][lane];
            int d0 = (r & 3) + 8 * (r >> 2) + 4 * g;
            ot[lq5 * 72 + d0]      = (bf16)(a0 * inv);
            ot[lq5 * 72 + d0 + 32] = (bf16)(a1 * inv);
        }
        __builtin_amdgcn_s_waitcnt(0);     // drain lgkm before same-wave readback
        #pragma unroll
        for (int i = 0; i < 4; i++) {
            int tq = i * 8 + (lane >> 3);
            bf16x8 ov = *(const bf16x8*)&ot[tq * 72 + (lane & 7) * 8];
            *(bf16x8*)&aout[(size_t)(n * 2048 + qt * 128 + qsub * 32 + tq) * 512
                            + h * 64 + (lane & 7) * 8] = ov;
        }
    }
}

extern "C" void kernel_launch(void* const* d_in, const int* in_sizes, int n_in,
                              void* d_out, int out_size, void* d_ws, size_t ws_size,
                              hipStream_t stream) {
    (void)in_sizes; (void)n_in; (void)out_size; (void)ws_size;
    const float* x   = (const float*)d_in[0];
    const float* wq  = (const float*)d_in[1];
    const float* wk  = (const float*)d_in[2];
    const float* wv  = (const float*)d_in[3];
    const float* wo  = (const float*)d_in[4];
    const float* bo  = (const float*)d_in[5];
    const float* g1  = (const float*)d_in[6];
    const float* b1  = (const float*)d_in[7];
    const float* g2  = (const float*)d_in[8];
    const float* b2  = (const float*)d_in[9];
    const float* w1  = (const float*)d_in[10];
    const float* bf1 = (const float*)d_in[11];
    const float* w2  = (const float*)d_in[12];
    const float* bf2 = (const float*)d_in[13];
    float* out = (float*)d_out;

    char* p = (char*)d_ws;
    bf16*  h1     = (bf16*)p;  p += (size_t)8192 * 512 * 2;    // LN out (reused)
    bf16*  qkvb   = (bf16*)p;  p += (size_t)8192 * 1536 * 2;   // packed Q|K|V
    bf16*  aout   = (bf16*)p;  p += (size_t)8192 * 512 * 2;    // attention out
    float* x2     = (float*)p; p += (size_t)8192 * 512 * 4;    // post-attn residual
    bf16*  ff1    = (bf16*)p;  p += (size_t)8192 * 2048 * 2;   // SiLU(h@w1+b)
    bf16*  wqkv_t = (bf16*)p;  p += (size_t)1536 * 512 * 2;
    bf16*  wo_t   = (bf16*)p;  p += (size_t)512 * 512 * 2;
    bf16*  w1_t   = (bf16*)p;  p += (size_t)2048 * 512 * 2;
    bf16*  w2_t   = (bf16*)p;  p += (size_t)512 * 2048 * 2;
    // Kfrag/Vfrag (8.4 MB each) alias the ff1 region: consumed before FF1 writes
    bf16*  Kfrag  = (bf16*)ff1;
    bf16*  Vfrag  = Kfrag + (size_t)8192 * 512;

    cvt_all<<<768, 256, 0, stream>>>(wq, wk, wv, wo, w1, w2, wqkv_t, wo_t, w1_t, w2_t);

    ln_kernel<<<2048, 256, 0, stream>>>(x, g1, b1, h1);
    gemm_k<512, 1536, 0><<<dim3(64, 12), 256, 0, stream>>>(h1, wqkv_t, nullptr, qkvb);
    pack_kv<<<1024, 256, 0, stream>>>(qkvb, Kfrag, Vfrag);
    attn_kernel<<<512, 512, 0, stream>>>(qkvb, Kfrag, Vfrag, aout);
    gemm64<512><<<dim3(128, 8), 256, 0, stream>>>(aout, wo_t, bo, x, x2);
    ln_kernel<<<2048, 256, 0, stream>>>(x2, g2, b2, h1);
    gemm_k<512, 2048, 2><<<dim3(64, 16), 256, 0, stream>>>(h1, w1_t, bf1, ff1);
    gemm64<2048><<<dim3(128, 8), 256, 0, stream>>>(ff1, w2_t, bf2, x2, out);
}